// Round 1
// baseline (858.484 us; speedup 1.0000x reference)
//
#include <hip/hip_runtime.h>

#define S_LEN 2048
#define D_MODEL 4096
#define N_HEADS 32
#define N_KV 8
#define HEAD_DIM 128

typedef float f32x4 __attribute__((ext_vector_type(4)));
typedef short bf16x8 __attribute__((ext_vector_type(8)));

__device__ __forceinline__ unsigned short f2bf(float f) {
  unsigned int u = __float_as_uint(f);
  unsigned int r = (u + 0x7fffu + ((u >> 16) & 1u)) >> 16;
  return (unsigned short)r;
}
__device__ __forceinline__ float bf2f(unsigned short b) {
  return __uint_as_float(((unsigned int)b) << 16);
}
__device__ __forceinline__ void gload_lds16(const void* g, void* l) {
  __builtin_amdgcn_global_load_lds((const __attribute__((address_space(1))) void*)g,
                                   (__attribute__((address_space(3))) void*)l, 16, 0, 0);
}

// ---------------- f32 -> bf16 convert (vectorized, grid-stride) ----------------
__global__ void cvt_f32_bf16(const float* __restrict__ in, unsigned short* __restrict__ out, int n4) {
  int stride = gridDim.x * blockDim.x;
  for (int i = blockIdx.x * blockDim.x + threadIdx.x; i < n4; i += stride) {
    float4 v = ((const float4*)in)[i];
    unsigned int lo = (unsigned int)f2bf(v.x) | ((unsigned int)f2bf(v.y) << 16);
    unsigned int hi = (unsigned int)f2bf(v.z) | ((unsigned int)f2bf(v.w) << 16);
    uint2 o; o.x = lo; o.y = hi;
    ((uint2*)out)[i] = o;
  }
}

// ---------------- f32 K x N  ->  bf16 N x K (transpose + convert) ----------------
__global__ void transpose_cvt(const float* __restrict__ in, unsigned short* __restrict__ out,
                              int K, int N) {
  __shared__ float tile[32][33];
  int k0 = blockIdx.y << 5, n0 = blockIdx.x << 5;
  int tx = threadIdx.x, ty = threadIdx.y;
#pragma unroll
  for (int r = 0; r < 32; r += 8)
    tile[ty + r][tx] = in[(k0 + ty + r) * N + n0 + tx];
  __syncthreads();
#pragma unroll
  for (int r = 0; r < 32; r += 8)
    out[(n0 + ty + r) * K + k0 + tx] = f2bf(tile[tx][ty + r]);
}

// ---------------- in-place RoPE on bf16 [S][ncols], pairs (2p, 2p+1) per head ----------------
__global__ void rope_k(unsigned short* __restrict__ t, const float* __restrict__ cb,
                       const float* __restrict__ sb, int ncols, int shift) {
  int idx = blockIdx.x * blockDim.x + threadIdx.x;  // one per pair, grid sized exactly
  int pos = idx >> shift;
  int wp = idx & ((1 << shift) - 1);
  int p = wp & 63;
  int col = ((wp >> 6) << 7) + (p << 1);
  unsigned int* addr = (unsigned int*)&t[pos * ncols + col];
  unsigned int pr = *addr;
  float t0 = bf2f((unsigned short)(pr & 0xffffu));
  float t1 = bf2f((unsigned short)(pr >> 16));
  float c = cb[pos * 64 + p], s = sb[pos * 64 + p];
  float o0 = t0 * c - t1 * s;
  float o1 = t0 * s + t1 * c;
  *addr = (unsigned int)f2bf(o0) | ((unsigned int)f2bf(o1) << 16);
}

// ---------------- GEMM: C[M x N] = A[M x K] * Bt[N x K]^T   (bf16 in, f32 acc) ----------------
__device__ __forceinline__ void store_out(unsigned short* p, float v) { *p = f2bf(v); }
__device__ __forceinline__ void store_out(float* p, float v) { *p = v; }

template <typename OT>
__global__ __launch_bounds__(256, 2) void gemm_bt(const unsigned short* __restrict__ A,
                                                  const unsigned short* __restrict__ Bt,
                                                  OT* __restrict__ C, int M, int N, int K) {
  __shared__ __align__(16) unsigned short As[128 * 32];
  __shared__ __align__(16) unsigned short Bs[128 * 32];
  const int tid = threadIdx.x;
  const int w = tid >> 6, l = tid & 63;
  const int lrow = l & 15, lk = l >> 4;
  const int m0 = blockIdx.y * 128, n0 = blockIdx.x * 128;
  const int wm = (w >> 1) * 64, wn = (w & 1) * 64;
  f32x4 acc[4][4] = {};

  for (int kt = 0; kt < K; kt += 32) {
    __syncthreads();
#pragma unroll
    for (int p = 0; p < 2; ++p) {
      int e = (p * 256 + tid) * 8;
      int r = e >> 5, c = e & 31;
      gload_lds16(&A[(m0 + r) * K + kt + c], (char*)As + p * 4096 + w * 1024);
      gload_lds16(&Bt[(n0 + r) * K + kt + c], (char*)Bs + p * 4096 + w * 1024);
    }
    __syncthreads();
    bf16x8 af[4], bfr[4];
#pragma unroll
    for (int i = 0; i < 4; ++i)
      af[i] = *(const bf16x8*)&As[(wm + i * 16 + lrow) * 32 + lk * 8];
#pragma unroll
    for (int j = 0; j < 4; ++j)
      bfr[j] = *(const bf16x8*)&Bs[(wn + j * 16 + lrow) * 32 + lk * 8];
#pragma unroll
    for (int i = 0; i < 4; ++i)
#pragma unroll
      for (int j = 0; j < 4; ++j)
        acc[i][j] = __builtin_amdgcn_mfma_f32_16x16x32_bf16(af[i], bfr[j], acc[i][j], 0, 0, 0);
  }
#pragma unroll
  for (int i = 0; i < 4; ++i)
#pragma unroll
    for (int j = 0; j < 4; ++j)
#pragma unroll
      for (int r = 0; r < 4; ++r) {
        int row = m0 + wm + i * 16 + lk * 4 + r;
        int col = n0 + wn + j * 16 + lrow;
        store_out(&C[row * N + col], acc[i][j][r]);
      }
}

// ---------------- causal GQA flash attention ----------------
// grid: (S/128, H). block: 256 (4 waves x 32 q-rows). KV tile = 64.
__global__ __launch_bounds__(256, 2) void attn_fwd(const unsigned short* __restrict__ Q,
                                                   const unsigned short* __restrict__ Kb,
                                                   const unsigned short* __restrict__ Vb,
                                                   unsigned short* __restrict__ Ctx) {
  __shared__ __align__(16) unsigned short Ks[64 * 128];   // [kv][hd]
  __shared__ __align__(16) unsigned short Vt[128 * 72];   // [hd][kv] padded to 72
  __shared__ __align__(16) unsigned short Ps[4][32 * 72]; // per-wave P, padded to 72

  const int tid = threadIdx.x, w = tid >> 6, l = tid & 63;
  const int lrow = l & 15, lk = l >> 4;
  const int qh = blockIdx.y;
  const int g = qh >> 2;  // kv head
  const int q0 = blockIdx.x * 128;
  const int wq0 = q0 + w * 32;
  const float scale = 0.08838834764831845f;  // 1/sqrt(128)

  // Q fragments live in registers for the whole block
  bf16x8 qf[2][4];
#pragma unroll
  for (int i = 0; i < 2; ++i)
#pragma unroll
    for (int ks = 0; ks < 4; ++ks)
      qf[i][ks] = *(const bf16x8*)&Q[(wq0 + i * 16 + lrow) * D_MODEL + qh * HEAD_DIM + ks * 32 + lk * 8];

  f32x4 o[2][8] = {};
  float mrun[2][4], lrun[2][4], al[2][4];
#pragma unroll
  for (int i = 0; i < 2; ++i)
#pragma unroll
    for (int r = 0; r < 4; ++r) { mrun[i][r] = -1e30f; lrun[i][r] = 0.0f; }

  const int nt = (q0 + 128) >> 6;
  for (int t = 0; t < nt; ++t) {
    const int kv0 = t << 6;
    __syncthreads();
    // stage K tile [64][128] via global_load_lds (linear)
#pragma unroll
    for (int p = 0; p < 4; ++p) {
      int e = (p * 256 + tid) * 8;
      int r = e >> 7, c = e & 127;
      gload_lds16(&Kb[(kv0 + r) * (N_KV * HEAD_DIM) + g * HEAD_DIM + c],
                  (char*)Ks + p * 4096 + w * 1024);
    }
    // stage V transposed: Vt[hd][kv]
#pragma unroll
    for (int p = 0; p < 4; ++p) {
      int kvr = p * 16 + (tid >> 4);
      int hc = (tid & 15) * 8;
      bf16x8 vv = *(const bf16x8*)&Vb[(kv0 + kvr) * (N_KV * HEAD_DIM) + g * HEAD_DIM + hc];
#pragma unroll
      for (int e2 = 0; e2 < 8; ++e2) Vt[(hc + e2) * 72 + kvr] = (unsigned short)vv[e2];
    }
    __syncthreads();

    // S = Q K^T  (per wave: 32 x 64)
    f32x4 sa[2][4] = {};
#pragma unroll
    for (int ks = 0; ks < 4; ++ks) {
      bf16x8 kf[4];
#pragma unroll
      for (int j = 0; j < 4; ++j)
        kf[j] = *(const bf16x8*)&Ks[(j * 16 + lrow) * 128 + ks * 32 + lk * 8];
#pragma unroll
      for (int i = 0; i < 2; ++i)
#pragma unroll
        for (int j = 0; j < 4; ++j)
          sa[i][j] = __builtin_amdgcn_mfma_f32_16x16x32_bf16(qf[i][ks], kf[j], sa[i][j], 0, 0, 0);
    }

    // online softmax (rows spread over 16-lane groups; 4 rows per lane per i-tile)
#pragma unroll
    for (int i = 0; i < 2; ++i)
#pragma unroll
      for (int r = 0; r < 4; ++r) {
        int qrow = wq0 + i * 16 + lk * 4 + r;
        float sv[4];
        float mx = -1e30f;
#pragma unroll
        for (int j = 0; j < 4; ++j) {
          float x = sa[i][j][r] * scale;
          int kvcol = kv0 + j * 16 + lrow;
          if (kvcol > qrow) x = -1e30f;
          sv[j] = x;
          mx = fmaxf(mx, x);
        }
#pragma unroll
        for (int d = 1; d < 16; d <<= 1) mx = fmaxf(mx, __shfl_xor(mx, d));
        float mold = mrun[i][r];
        float mnew = fmaxf(mold, mx);
        float alpha = __expf(mold - mnew);
        float rs = 0.0f;
        float ps[4];
#pragma unroll
        for (int j = 0; j < 4; ++j) { ps[j] = __expf(sv[j] - mnew); rs += ps[j]; }
#pragma unroll
        for (int d = 1; d < 16; d <<= 1) rs += __shfl_xor(rs, d);
        mrun[i][r] = mnew;
        lrun[i][r] = lrun[i][r] * alpha + rs;
        al[i][r] = alpha;
#pragma unroll
        for (int j = 0; j < 4; ++j)
          Ps[w][(i * 16 + lk * 4 + r) * 72 + j * 16 + lrow] = f2bf(ps[j]);
      }

    // rescale O
#pragma unroll
    for (int i = 0; i < 2; ++i)
#pragma unroll
      for (int n = 0; n < 8; ++n)
#pragma unroll
        for (int r = 0; r < 4; ++r) o[i][n][r] *= al[i][r];

    // O += P V   (P from per-wave LDS, V from transposed tile)
#pragma unroll
    for (int ks = 0; ks < 2; ++ks) {
      bf16x8 pa[2];
#pragma unroll
      for (int i = 0; i < 2; ++i)
        pa[i] = *(const bf16x8*)&Ps[w][(i * 16 + lrow) * 72 + ks * 32 + lk * 8];
#pragma unroll
      for (int n = 0; n < 8; ++n) {
        bf16x8 vf = *(const bf16x8*)&Vt[(n * 16 + lrow) * 72 + ks * 32 + lk * 8];
#pragma unroll
        for (int i = 0; i < 2; ++i)
          o[i][n] = __builtin_amdgcn_mfma_f32_16x16x32_bf16(pa[i], vf, o[i][n], 0, 0, 0);
      }
    }
  }

  // epilogue: O / l  -> ctx (bf16)
#pragma unroll
  for (int i = 0; i < 2; ++i) {
    float inv[4];
#pragma unroll
    for (int r = 0; r < 4; ++r) inv[r] = 1.0f / lrun[i][r];
#pragma unroll
    for (int n = 0; n < 8; ++n)
#pragma unroll
      for (int r = 0; r < 4; ++r) {
        int row = wq0 + i * 16 + lk * 4 + r;
        int col = n * 16 + lrow;
        Ctx[row * D_MODEL + qh * HEAD_DIM + col] = f2bf(o[i][n][r] * inv[r]);
      }
  }
}

// ---------------- host launch ----------------
extern "C" void kernel_launch(void* const* d_in, const int* in_sizes, int n_in,
                              void* d_out, int out_size, void* d_ws, size_t ws_size,
                              hipStream_t stream) {
  const float* x = (const float*)d_in[0];
  const float* wq = (const float*)d_in[1];
  const float* wk = (const float*)d_in[2];
  const float* wv = (const float*)d_in[3];
  const float* wo = (const float*)d_in[4];
  const float* fcos = (const float*)d_in[5];
  const float* fsin = (const float*)d_in[6];
  float* out = (float*)d_out;

  char* ws = (char*)d_ws;
  unsigned short* xb = (unsigned short*)ws;                       // 2048*4096 bf16
  unsigned short* ctx = xb;                                       // alias (x dead by then)
  unsigned short* wt = (unsigned short*)(ws + (size_t)16777216);  // 4096*4096 bf16
  unsigned short* qb = (unsigned short*)(ws + (size_t)16777216 + 33554432);
  unsigned short* kb = qb + (size_t)S_LEN * D_MODEL;
  unsigned short* vb = kb + (size_t)S_LEN * N_KV * HEAD_DIM;

  // x -> bf16
  cvt_f32_bf16<<<2048, 256, 0, stream>>>(x, xb, S_LEN * D_MODEL / 4);

  // Q = x @ wq
  transpose_cvt<<<dim3(4096 / 32, 4096 / 32), dim3(32, 8), 0, stream>>>(wq, wt, 4096, 4096);
  gemm_bt<unsigned short><<<dim3(4096 / 128, S_LEN / 128), 256, 0, stream>>>(xb, wt, qb, S_LEN, 4096, 4096);
  // K = x @ wk
  transpose_cvt<<<dim3(1024 / 32, 4096 / 32), dim3(32, 8), 0, stream>>>(wk, wt, 4096, 1024);
  gemm_bt<unsigned short><<<dim3(1024 / 128, S_LEN / 128), 256, 0, stream>>>(xb, wt, kb, S_LEN, 1024, 4096);
  // V = x @ wv
  transpose_cvt<<<dim3(1024 / 32, 4096 / 32), dim3(32, 8), 0, stream>>>(wv, wt, 4096, 1024);
  gemm_bt<unsigned short><<<dim3(1024 / 128, S_LEN / 128), 256, 0, stream>>>(xb, wt, vb, S_LEN, 1024, 4096);

  // RoPE in-place on q, k
  rope_k<<<(S_LEN * (D_MODEL / 2)) / 256, 256, 0, stream>>>(qb, fcos, fsin, D_MODEL, 11);
  rope_k<<<(S_LEN * (N_KV * HEAD_DIM / 2)) / 256, 256, 0, stream>>>(kb, fcos, fsin, N_KV * HEAD_DIM, 9);

  // attention
  attn_fwd<<<dim3(S_LEN / 128, N_HEADS), 256, 0, stream>>>(qb, kb, vb, ctx);

  // out = ctx @ wo  (f32 output)
  transpose_cvt<<<dim3(4096 / 32, 4096 / 32), dim3(32, 8), 0, stream>>>(wo, wt, 4096, 4096);
  gemm_bt<float><<<dim3(4096 / 128, S_LEN / 128), 256, 0, stream>>>(ctx, wt, out, S_LEN, 4096, 4096);
}

// Round 2
// 646.004 us; speedup vs baseline: 1.3289x; 1.3289x over previous
//
#include <hip/hip_runtime.h>

#define S_LEN 2048
#define D_MODEL 4096
#define N_HEADS 32
#define N_KV 8
#define HEAD_DIM 128

typedef float f32x4 __attribute__((ext_vector_type(4)));
typedef short bf16x8 __attribute__((ext_vector_type(8)));

__device__ __forceinline__ unsigned short f2bf(float f) {
  unsigned int u = __float_as_uint(f);
  unsigned int r = (u + 0x7fffu + ((u >> 16) & 1u)) >> 16;
  return (unsigned short)r;
}
__device__ __forceinline__ float bf2f(unsigned short b) {
  return __uint_as_float(((unsigned int)b) << 16);
}
__device__ __forceinline__ void gload_lds16(const void* g, void* l) {
  __builtin_amdgcn_global_load_lds((const __attribute__((address_space(1))) void*)g,
                                   (__attribute__((address_space(3))) void*)l, 16, 0, 0);
}

// ---------------- f32 -> bf16 convert (vectorized, grid-stride) ----------------
__global__ void cvt_f32_bf16(const float* __restrict__ in, unsigned short* __restrict__ out, int n4) {
  int stride = gridDim.x * blockDim.x;
  for (int i = blockIdx.x * blockDim.x + threadIdx.x; i < n4; i += stride) {
    float4 v = ((const float4*)in)[i];
    unsigned int lo = (unsigned int)f2bf(v.x) | ((unsigned int)f2bf(v.y) << 16);
    unsigned int hi = (unsigned int)f2bf(v.z) | ((unsigned int)f2bf(v.w) << 16);
    uint2 o; o.x = lo; o.y = hi;
    ((uint2*)out)[i] = o;
  }
}

// ---------------- f32 K x N  ->  bf16 N x K (transpose + convert) ----------------
__global__ void transpose_cvt(const float* __restrict__ in, unsigned short* __restrict__ out,
                              int K, int N) {
  __shared__ float tile[32][33];
  int k0 = blockIdx.y << 5, n0 = blockIdx.x << 5;
  int tx = threadIdx.x, ty = threadIdx.y;
#pragma unroll
  for (int r = 0; r < 32; r += 8)
    tile[ty + r][tx] = in[(k0 + ty + r) * N + n0 + tx];
  __syncthreads();
#pragma unroll
  for (int r = 0; r < 32; r += 8)
    out[(n0 + ty + r) * K + k0 + tx] = f2bf(tile[tx][ty + r]);
}

// ---------------- bf16 transpose: out[c][r] = in[r][col0 + c] ----------------
__global__ void transpose_bf16(const unsigned short* __restrict__ in, unsigned short* __restrict__ out,
                               int inStride, int outStride, int col0) {
  __shared__ unsigned short tile[32][33];
  int r0 = blockIdx.y << 5, c0 = blockIdx.x << 5;
  int tx = threadIdx.x, ty = threadIdx.y;
#pragma unroll
  for (int r = 0; r < 32; r += 8)
    tile[ty + r][tx] = in[(r0 + ty + r) * inStride + col0 + c0 + tx];
  __syncthreads();
#pragma unroll
  for (int r = 0; r < 32; r += 8)
    out[(c0 + ty + r) * outStride + r0 + tx] = tile[tx][ty + r];
}

// ---------------- in-place RoPE on bf16 [S][rowStride], pairs (2p, 2p+1) per head ----------------
__global__ void rope_k(unsigned short* __restrict__ t, const float* __restrict__ cb,
                       const float* __restrict__ sb, int rowStride, int shift) {
  int idx = blockIdx.x * blockDim.x + threadIdx.x;
  int pos = idx >> shift;
  int wp = idx & ((1 << shift) - 1);
  int p = wp & 63;
  int col = ((wp >> 6) << 7) + (p << 1);
  unsigned int* addr = (unsigned int*)&t[pos * rowStride + col];
  unsigned int pr = *addr;
  float t0 = bf2f((unsigned short)(pr & 0xffffu));
  float t1 = bf2f((unsigned short)(pr >> 16));
  float c = cb[pos * 64 + p], s = sb[pos * 64 + p];
  float o0 = t0 * c - t1 * s;
  float o1 = t0 * s + t1 * c;
  *addr = (unsigned int)f2bf(o0) | ((unsigned int)f2bf(o1) << 16);
}

// ---------------- GEMM: C[M x N] = A[M x K] * Bt[N x K]^T   (bf16 in, f32 acc) ----------------
__device__ __forceinline__ void store_out(unsigned short* p, float v) { *p = f2bf(v); }
__device__ __forceinline__ void store_out(float* p, float v) { *p = v; }

template <typename OT>
__global__ __launch_bounds__(256, 2) void gemm_bt(const unsigned short* __restrict__ A,
                                                  const unsigned short* __restrict__ Bt,
                                                  OT* __restrict__ C, int M, int N, int K) {
  __shared__ __align__(16) unsigned short As[128 * 32];
  __shared__ __align__(16) unsigned short Bs[128 * 32];
  const int tid = threadIdx.x;
  const int w = tid >> 6, l = tid & 63;
  const int lrow = l & 15, lk = l >> 4;
  const int m0 = blockIdx.y * 128, n0 = blockIdx.x * 128;
  const int wm = (w >> 1) * 64, wn = (w & 1) * 64;
  f32x4 acc[4][4] = {};

  for (int kt = 0; kt < K; kt += 32) {
    __syncthreads();
#pragma unroll
    for (int p = 0; p < 2; ++p) {
      int e = (p * 256 + tid) * 8;
      int r = e >> 5, c = e & 31;
      gload_lds16(&A[(m0 + r) * K + kt + c], (char*)As + p * 4096 + w * 1024);
      gload_lds16(&Bt[(n0 + r) * K + kt + c], (char*)Bs + p * 4096 + w * 1024);
    }
    __syncthreads();
    bf16x8 af[4], bfr[4];
#pragma unroll
    for (int i = 0; i < 4; ++i)
      af[i] = *(const bf16x8*)&As[(wm + i * 16 + lrow) * 32 + lk * 8];
#pragma unroll
    for (int j = 0; j < 4; ++j)
      bfr[j] = *(const bf16x8*)&Bs[(wn + j * 16 + lrow) * 32 + lk * 8];
#pragma unroll
    for (int i = 0; i < 4; ++i)
#pragma unroll
      for (int j = 0; j < 4; ++j)
        acc[i][j] = __builtin_amdgcn_mfma_f32_16x16x32_bf16(af[i], bfr[j], acc[i][j], 0, 0, 0);
  }
#pragma unroll
  for (int i = 0; i < 4; ++i)
#pragma unroll
    for (int j = 0; j < 4; ++j)
#pragma unroll
      for (int r = 0; r < 4; ++r) {
        int row = m0 + wm + i * 16 + lk * 4 + r;
        int col = n0 + wn + j * 16 + lrow;
        store_out(&C[row * N + col], acc[i][j][r]);
      }
}

// ---------------- causal GQA flash attention ----------------
// grid: (S/128, H). block: 256 (4 waves x 32 q-rows). KV tile = 64.
// K staged [64][128] XOR-swizzled; V staged from global V^T as [128][64] XOR-swizzled.
__global__ __launch_bounds__(256, 2) void attn_fwd(const unsigned short* __restrict__ Q,
                                                   const unsigned short* __restrict__ Kb,
                                                   const unsigned short* __restrict__ Vt,
                                                   unsigned short* __restrict__ Ctx) {
  __shared__ __align__(16) unsigned short Ks[64 * 128];   // [kv][hd], chunk^=(row&7)
  __shared__ __align__(16) unsigned short Vs[128 * 64];   // [hd][kv], chunk^=(row&7)
  __shared__ __align__(16) unsigned short Ps[4][32 * 72]; // per-wave P, pad 72

  const int tid = threadIdx.x, w = tid >> 6, l = tid & 63;
  const int lrow = l & 15, lk = l >> 4;
  const int qh = blockIdx.y;
  const int g = qh >> 2;  // kv head
  const int qbi = gridDim.x - 1 - blockIdx.x;  // heavy (high-q) blocks first
  const int q0 = qbi * 128;
  const int wq0 = q0 + w * 32;
  const float scale = 0.08838834764831845f;  // 1/sqrt(128)
  const int kvStride = N_KV * HEAD_DIM;      // 1024? no: kvb row stride
  (void)kvStride;

  // Q fragments live in registers for the whole block
  bf16x8 qf[2][4];
#pragma unroll
  for (int i = 0; i < 2; ++i)
#pragma unroll
    for (int ks = 0; ks < 4; ++ks)
      qf[i][ks] = *(const bf16x8*)&Q[(wq0 + i * 16 + lrow) * D_MODEL + qh * HEAD_DIM + ks * 32 + lk * 8];

  f32x4 o[2][8] = {};
  float mrun[2][4], lrun[2][4], al[2][4];
#pragma unroll
  for (int i = 0; i < 2; ++i)
#pragma unroll
    for (int r = 0; r < 4; ++r) { mrun[i][r] = -1e30f; lrun[i][r] = 0.0f; }

  const int nt = (q0 + 128) >> 6;
  for (int t = 0; t < nt; ++t) {
    const int kv0 = t << 6;
    __syncthreads();
    // stage K tile [64][128]: linear LDS dest, inverse-swizzled global source (rule #21)
#pragma unroll
    for (int p = 0; p < 4; ++p) {
      int o_b = p * 4096 + w * 1024 + (l << 4);  // this lane's linear LDS byte offset
      int row = o_b >> 8;                        // 256B rows
      int sc = ((o_b >> 4) & 15) ^ (row & 7);    // source 16B chunk
      gload_lds16(&Kb[(kv0 + row) * 2048 + g * HEAD_DIM + sc * 8],
                  (char*)Ks + p * 4096 + w * 1024);
    }
    // stage V^T tile [128][64] from global Vt [1024][2048]
#pragma unroll
    for (int p = 0; p < 4; ++p) {
      int o_b = p * 4096 + w * 1024 + (l << 4);
      int row = o_b >> 7;                        // 128B rows (hd index)
      int sc = ((o_b >> 4) & 7) ^ (row & 7);
      gload_lds16(&Vt[(g * HEAD_DIM + row) * 2048 + kv0 + sc * 8],
                  (char*)Vs + p * 4096 + w * 1024);
    }
    __syncthreads();

    // S = Q K^T  (per wave: 32 x 64)
    f32x4 sa[2][4] = {};
#pragma unroll
    for (int ks = 0; ks < 4; ++ks) {
      bf16x8 kf[4];
#pragma unroll
      for (int j = 0; j < 4; ++j) {
        int row = j * 16 + lrow;
        kf[j] = *(const bf16x8*)&Ks[row * 128 + ((ks * 32 + lk * 8) ^ ((row & 7) << 3))];
      }
#pragma unroll
      for (int i = 0; i < 2; ++i)
#pragma unroll
        for (int j = 0; j < 4; ++j)
          sa[i][j] = __builtin_amdgcn_mfma_f32_16x16x32_bf16(qf[i][ks], kf[j], sa[i][j], 0, 0, 0);
    }

    // online softmax (rows spread over 16-lane groups; 4 rows per lane per i-tile)
#pragma unroll
    for (int i = 0; i < 2; ++i)
#pragma unroll
      for (int r = 0; r < 4; ++r) {
        int qrow = wq0 + i * 16 + lk * 4 + r;
        float sv[4];
        float mx = -1e30f;
#pragma unroll
        for (int j = 0; j < 4; ++j) {
          float x = sa[i][j][r] * scale;
          int kvcol = kv0 + j * 16 + lrow;
          if (kvcol > qrow) x = -1e30f;
          sv[j] = x;
          mx = fmaxf(mx, x);
        }
#pragma unroll
        for (int d = 1; d < 16; d <<= 1) mx = fmaxf(mx, __shfl_xor(mx, d));
        float mold = mrun[i][r];
        float mnew = fmaxf(mold, mx);
        float alpha = __expf(mold - mnew);
        float rs = 0.0f;
        float ps[4];
#pragma unroll
        for (int j = 0; j < 4; ++j) { ps[j] = __expf(sv[j] - mnew); rs += ps[j]; }
#pragma unroll
        for (int d = 1; d < 16; d <<= 1) rs += __shfl_xor(rs, d);
        mrun[i][r] = mnew;
        lrun[i][r] = lrun[i][r] * alpha + rs;
        al[i][r] = alpha;
#pragma unroll
        for (int j = 0; j < 4; ++j)
          Ps[w][(i * 16 + lk * 4 + r) * 72 + j * 16 + lrow] = f2bf(ps[j]);
      }

    // rescale O
#pragma unroll
    for (int i = 0; i < 2; ++i)
#pragma unroll
      for (int n = 0; n < 8; ++n)
#pragma unroll
        for (int r = 0; r < 4; ++r) o[i][n][r] *= al[i][r];

    // O += P V   (P from per-wave LDS; V^T fragments from swizzled Vs)
#pragma unroll
    for (int ks = 0; ks < 2; ++ks) {
      bf16x8 pa[2];
#pragma unroll
      for (int i = 0; i < 2; ++i)
        pa[i] = *(const bf16x8*)&Ps[w][(i * 16 + lrow) * 72 + ks * 32 + lk * 8];
#pragma unroll
      for (int n = 0; n < 8; ++n) {
        int row = n * 16 + lrow;
        bf16x8 vf = *(const bf16x8*)&Vs[row * 64 + ((ks * 32 + lk * 8) ^ ((row & 7) << 3))];
#pragma unroll
        for (int i = 0; i < 2; ++i)
          o[i][n] = __builtin_amdgcn_mfma_f32_16x16x32_bf16(pa[i], vf, o[i][n], 0, 0, 0);
      }
    }
  }

  // epilogue: O / l  -> ctx (bf16)
#pragma unroll
  for (int i = 0; i < 2; ++i) {
    float inv[4];
#pragma unroll
    for (int r = 0; r < 4; ++r) inv[r] = 1.0f / lrun[i][r];
#pragma unroll
    for (int n = 0; n < 8; ++n)
#pragma unroll
      for (int r = 0; r < 4; ++r) {
        int row = wq0 + i * 16 + lk * 4 + r;
        int col = n * 16 + lrow;
        Ctx[row * D_MODEL + qh * HEAD_DIM + col] = f2bf(o[i][n][r] * inv[r]);
      }
  }
}

// ---------------- host launch ----------------
extern "C" void kernel_launch(void* const* d_in, const int* in_sizes, int n_in,
                              void* d_out, int out_size, void* d_ws, size_t ws_size,
                              hipStream_t stream) {
  const float* x = (const float*)d_in[0];
  const float* wq = (const float*)d_in[1];
  const float* wk = (const float*)d_in[2];
  const float* wv = (const float*)d_in[3];
  const float* wo = (const float*)d_in[4];
  const float* fcos = (const float*)d_in[5];
  const float* fsin = (const float*)d_in[6];
  float* out = (float*)d_out;

  char* ws = (char*)d_ws;
  unsigned short* xb = (unsigned short*)ws;                      // 16MB: x bf16; later ctx
  unsigned short* ctx = xb;
  unsigned short* wt = (unsigned short*)(ws + (size_t)16 * 1024 * 1024);   // 32MB weights^T
  unsigned short* qb = (unsigned short*)(ws + (size_t)48 * 1024 * 1024);   // 16MB Q
  unsigned short* kvb = (unsigned short*)(ws + (size_t)64 * 1024 * 1024);  // 8MB K|V [2048][2048]
  unsigned short* vtg = (unsigned short*)(ws + (size_t)72 * 1024 * 1024);  // 4MB V^T [1024][2048]

  // x -> bf16
  cvt_f32_bf16<<<2048, 256, 0, stream>>>(x, xb, S_LEN * D_MODEL / 4);

  // Q = x @ wq
  transpose_cvt<<<dim3(128, 128), dim3(32, 8), 0, stream>>>(wq, wt, 4096, 4096);
  gemm_bt<unsigned short><<<dim3(32, 16), 256, 0, stream>>>(xb, wt, qb, S_LEN, 4096, 4096);

  // K|V = x @ [wk|wv]  (fused, N=2048)
  transpose_cvt<<<dim3(32, 128), dim3(32, 8), 0, stream>>>(wk, wt, 4096, 1024);
  transpose_cvt<<<dim3(32, 128), dim3(32, 8), 0, stream>>>(wv, wt + (size_t)1024 * 4096, 4096, 1024);
  gemm_bt<unsigned short><<<dim3(16, 16), 256, 0, stream>>>(xb, wt, kvb, S_LEN, 2048, 4096);

  // RoPE in-place on Q and K
  rope_k<<<(S_LEN * 2048) / 256, 256, 0, stream>>>(qb, fcos, fsin, 4096, 11);
  rope_k<<<(S_LEN * 512) / 256, 256, 0, stream>>>(kvb, fcos, fsin, 2048, 9);

  // V^T in global: vtg[c][r] = kvb[r][1024 + c]
  transpose_bf16<<<dim3(32, 64), dim3(32, 8), 0, stream>>>(kvb, vtg, 2048, 2048, 1024);

  // attention
  attn_fwd<<<dim3(S_LEN / 128, N_HEADS), 256, 0, stream>>>(qb, kvb, vtg, ctx);

  // out = ctx @ wo  (f32 output)
  transpose_cvt<<<dim3(128, 128), dim3(32, 8), 0, stream>>>(wo, wt, 4096, 4096);
  gemm_bt<float><<<dim3(32, 16), 256, 0, stream>>>(ctx, wt, out, S_LEN, 4096, 4096);
}